// Round 13
// baseline (755.415 us; speedup 1.0000x reference)
//
#include <hip/hip_runtime.h>
#include <hip/hip_bf16.h>
#include <cstdint>
#include <cstddef>

#define D 128
#define NNODES 200000
#define NEDGES 500000
#define NLAYERS 5
#define BN_EPS 1e-5f
#define MAXDEG 24

typedef __attribute__((ext_vector_type(8))) short bf16x8;   // 8 bf16 in 4 VGPRs
typedef __attribute__((ext_vector_type(4))) float f32x4;    // MFMA accumulator

__device__ __forceinline__ unsigned short f2bf(float f) {
    union { float f; unsigned int u; } x; x.f = f;
    unsigned int r = (x.u + 0x7FFFu + ((x.u >> 16) & 1u)) >> 16;   // RNE
    return (unsigned short)r;
}
__device__ __forceinline__ float bf2f(unsigned short u) {
    union { unsigned int u; float f; } x; x.u = ((unsigned int)u) << 16; return x.f;
}

// ---------------- CSR build ----------------
__global__ void k_zero(int* __restrict__ p, int n) {
    int i = blockIdx.x * 256 + threadIdx.x;
    if (i < n) p[i] = 0;
}

// pack src (18 bits) + a0,a1,a2 (3 bits each) into one int per edge
__global__ void k_fill_edges(const int* __restrict__ ei, const int* __restrict__ ea,
                             int* __restrict__ deg, int* __restrict__ elist, int n_edges) {
    int e = blockIdx.x * 256 + threadIdx.x;
    if (e >= n_edges) return;
    int dst = ei[n_edges + e];
    int src = ei[e];
    int a0 = ea[e * 3], a1 = ea[e * 3 + 1], a2 = ea[e * 3 + 2];
    int rec = src | (a0 << 18) | (a1 << 21) | (a2 << 24);
    int pos = atomicAdd(&deg[dst], 1);
    if (pos < MAXDEG) elist[dst * MAXDEG + pos] = rec;
}

// ---------------- weight prep: fp32 [K][F] -> bf16 transposed [F][K] ----------------
__global__ void k_prep_w(const float* __restrict__ aeW2, const float* __restrict__ aeW3,
                         const float* __restrict__ mlpW1, const float* __restrict__ mlpW2,
                         unsigned short* __restrict__ wbt) {
    int m = blockIdx.x >> 3;                        // 0..11
    int s = (blockIdx.x & 7) * 256 + threadIdx.x;   // 0..2047
    int f = s >> 4;
    int kc = (s & 15) * 8;
    const float* W;
    if (m == 0) W = aeW2;
    else if (m == 1) W = aeW3;
    else if (m < 7) W = mlpW1 + (size_t)(m - 2) * D * D;
    else W = mlpW2 + (size_t)(m - 7) * D * D;
    unsigned short tmp[8];
#pragma unroll
    for (int j = 0; j < 8; ++j) tmp[j] = f2bf(W[(size_t)(kc + j) * D + f]);
    *(int4*)(wbt + (size_t)m * D * D + (size_t)f * D + kc) = *(int4*)tmp;
}

// ---------------- bond-sum table (bf16): bsum[l][combo][f] ----------------
// combo = a0 | a1<<3 | a2<<6  (matches rec bits 18..26)
__global__ void k_bondsum(const float* __restrict__ bond, unsigned short* __restrict__ bsum) {
    int idx = blockIdx.x;                 // 0..(NLAYERS*512-1)
    int l = idx >> 9, combo = idx & 511;
    int a0 = combo & 7, a1 = (combo >> 3) & 7, a2 = (combo >> 6) & 7;
    int f = threadIdx.x;                  // 128
    const float* bl = bond + (size_t)l * 3 * 8 * 128;
    bsum[(size_t)idx * 128 + f] =
        f2bf(bl[a0 * 128 + f] + bl[1024 + a1 * 128 + f] + bl[2048 + a2 * 128 + f]);
}

// ---------------- atom encoder layer 1 (persistent, BN folded, bf16 out) ----------------
__global__ void k_ae1(const float* __restrict__ x, const float* __restrict__ W,
                      const float* __restrict__ b, const float* __restrict__ g,
                      const float* __restrict__ be, const float* __restrict__ m,
                      const float* __restrict__ v, unsigned short* __restrict__ out) {
    __shared__ float sW[12][128];
    int tid = threadIdx.x;
    for (int i = tid; i < 12 * 128; i += 256) sW[i >> 7][i & 127] = W[i];
    int f0 = (tid & 31) * 4;
    int g8 = tid >> 5;
    float4 bb = *(const float4*)(b + f0);
    float4 gg = *(const float4*)(g + f0);
    float4 ee = *(const float4*)(be + f0);
    float4 mm = *(const float4*)(m + f0);
    float4 vv = *(const float4*)(v + f0);
    float A0 = gg.x * rsqrtf(vv.x + BN_EPS), S0 = (bb.x - mm.x) * A0 + ee.x;
    float A1 = gg.y * rsqrtf(vv.y + BN_EPS), S1 = (bb.y - mm.y) * A1 + ee.y;
    float A2 = gg.z * rsqrtf(vv.z + BN_EPS), S2 = (bb.z - mm.z) * A2 + ee.z;
    float A3 = gg.w * rsqrtf(vv.w + BN_EPS), S3 = (bb.w - mm.w) * A3 + ee.w;
    __syncthreads();
    for (int n = blockIdx.x * 8 + g8; n < NNODES; n += gridDim.x * 8) {
        const float4* xr = (const float4*)(x + (size_t)n * 12);
        float4 x0 = xr[0], x1 = xr[1], x2 = xr[2];
        float xv[12] = {x0.x, x0.y, x0.z, x0.w, x1.x, x1.y, x1.z, x1.w,
                        x2.x, x2.y, x2.z, x2.w};
        float a0 = 0.f, a1 = 0.f, a2 = 0.f, a3 = 0.f;
#pragma unroll
        for (int k = 0; k < 12; ++k) {
            float4 wv = *(float4*)&sW[k][f0];
            a0 += xv[k] * wv.x; a1 += xv[k] * wv.y;
            a2 += xv[k] * wv.z; a3 += xv[k] * wv.w;
        }
        unsigned short o[4];
        o[0] = f2bf(fmaxf(a0 * A0 + S0, 0.f));
        o[1] = f2bf(fmaxf(a1 * A1 + S1, 0.f));
        o[2] = f2bf(fmaxf(a2 * A2 + S2, 0.f));
        o[3] = f2bf(fmaxf(a3 * A3 + S3, 0.f));
        *(uint2*)(out + (size_t)n * D + f0) = *(uint2*)o;
    }
}

#define SWZ(row, bytecol) (((row) * 256 + (bytecol)) ^ (((row) & 7) << 4))

// ---------------- plain fused double GEMM (atom encoder): 64-node tile, 512 threads ----------------
template<int OUTF32>
__launch_bounds__(512, 6)
__global__ void k_mlp2(const unsigned short* __restrict__ hin,
                       const unsigned short* __restrict__ W1t, const float* __restrict__ b1,
                       const float* __restrict__ g1, const float* __restrict__ be1,
                       const float* __restrict__ m1, const float* __restrict__ v1,
                       const unsigned short* __restrict__ W2t, const float* __restrict__ b2,
                       const float* __restrict__ g2, const float* __restrict__ be2,
                       const float* __restrict__ m2, const float* __restrict__ v2,
                       unsigned short* __restrict__ outb, float* __restrict__ outf,
                       int do_bn2, int do_relu2) {
    __shared__ char sA[16384];
    __shared__ char sZ[16384];
    int tid = threadIdx.x;
    size_t nb = (size_t)blockIdx.x * 64;
    int lane = tid & 63;
    int w = tid >> 6;
    int arow = lane & 15;
    int kq = (lane >> 4) * 8;
    int c = w * 16 + arow;

    bf16x8 w1f[4], w2f[4];
#pragma unroll
    for (int kb = 0; kb < 4; ++kb) {
        w1f[kb] = *(const bf16x8*)(W1t + (size_t)c * D + kb * 32 + kq);
        w2f[kb] = *(const bf16x8*)(W2t + (size_t)c * D + kb * 32 + kq);
    }
#pragma unroll
    for (int i = 0; i < 2; ++i) {
        int s = tid + i * 512;
        int r = s >> 4, cc = (s & 15) * 16;
        *(int4*)(sA + SWZ(r, cc)) = *(const int4*)((const char*)hin + (nb + r) * 256 + cc);
    }
    __syncthreads();

    f32x4 acc[4];
#pragma unroll
    for (int rt = 0; rt < 4; ++rt) acc[rt] = (f32x4){0.f, 0.f, 0.f, 0.f};
#pragma unroll
    for (int kb = 0; kb < 4; ++kb) {
        int k0 = kb * 32 + kq;
#pragma unroll
        for (int rt = 0; rt < 4; ++rt) {
            bf16x8 a = *(bf16x8*)(sA + SWZ(rt * 16 + arow, k0 * 2));
            acc[rt] = __builtin_amdgcn_mfma_f32_16x16x32_bf16(a, w1f[kb], acc[rt], 0, 0, 0);
        }
    }
    {
        float sc = g1[c] * rsqrtf(v1[c] + BN_EPS);
        float sh = (b1[c] - m1[c]) * sc + be1[c];
#pragma unroll
        for (int rt = 0; rt < 4; ++rt)
#pragma unroll
            for (int r = 0; r < 4; ++r) {
                int row = rt * 16 + (lane >> 4) * 4 + r;
                float z = fmaxf(acc[rt][r] * sc + sh, 0.f);
                *(unsigned short*)(sZ + SWZ(row, c * 2)) = f2bf(z);
            }
    }
    __syncthreads();

#pragma unroll
    for (int rt = 0; rt < 4; ++rt) acc[rt] = (f32x4){0.f, 0.f, 0.f, 0.f};
#pragma unroll
    for (int kb = 0; kb < 4; ++kb) {
        int k0 = kb * 32 + kq;
#pragma unroll
        for (int rt = 0; rt < 4; ++rt) {
            bf16x8 a = *(bf16x8*)(sZ + SWZ(rt * 16 + arow, k0 * 2));
            acc[rt] = __builtin_amdgcn_mfma_f32_16x16x32_bf16(a, w2f[kb], acc[rt], 0, 0, 0);
        }
    }

    float sc2 = 1.f, sh2;
    if (do_bn2) { sc2 = g2[c] * rsqrtf(v2[c] + BN_EPS); sh2 = (b2[c] - m2[c]) * sc2 + be2[c]; }
    else sh2 = b2[c];
    if constexpr (OUTF32) {
#pragma unroll
        for (int rt = 0; rt < 4; ++rt)
#pragma unroll
            for (int r = 0; r < 4; ++r) {
                int row = rt * 16 + (lane >> 4) * 4 + r;
                float z = acc[rt][r] * sc2 + sh2;
                if (do_relu2) z = fmaxf(z, 0.f);
                outf[(nb + row) * D + c] = z;
            }
    } else {
#pragma unroll
        for (int rt = 0; rt < 4; ++rt)
#pragma unroll
            for (int r = 0; r < 4; ++r) {
                int row = rt * 16 + (lane >> 4) * 4 + r;
                float z = acc[rt][r] * sc2 + sh2;
                if (do_relu2) z = fmaxf(z, 0.f);
                *(unsigned short*)(sA + SWZ(row, c * 2)) = f2bf(z);
            }
        __syncthreads();
#pragma unroll
        for (int i = 0; i < 2; ++i) {
            int s = tid + i * 512;
            int r = s >> 4, cc = (s & 15) * 16;
            *(int4*)((char*)outb + (nb + r) * 256 + cc) = *(int4*)(sA + SWZ(r, cc));
        }
    }
}

// ---------------- FUSED GIN layer: gather-aggregate -> double GEMM, one dispatch ----------------
// Phase 1: 32 groups x 16 lanes; each group aggregates 2 nodes (serial) -> the per-group
// dependent-gather chain is 2 round-trips (was 4 with 32-lane groups). Each lane covers
// 16B (8 bf16) of the row; 4-deep batch = 32 VGPR payload (P(deg<=4)=89%); shfl tail to
// 16 edges; direct-load tail beyond (P ~ 1e-9). (512,6): VGPR cap ~85 -> no spill.
// Phase 2: W frags global->reg (L2-hot), GEMM1 -> sZ -> GEMM2 -> out.
template<int OUTF32>
__launch_bounds__(512, 6)
__global__ void k_gin2(const unsigned short* __restrict__ hin,
                       const unsigned short* __restrict__ bsum,   // bf16 [512][128] this layer
                       const float* __restrict__ eps_arr, int layer,
                       const int* __restrict__ deg, const int* __restrict__ elist,
                       const unsigned short* __restrict__ W1t, const float* __restrict__ b1,
                       const float* __restrict__ g1, const float* __restrict__ be1,
                       const float* __restrict__ m1, const float* __restrict__ v1,
                       const unsigned short* __restrict__ W2t, const float* __restrict__ b2,
                       const float* __restrict__ g2, const float* __restrict__ be2,
                       const float* __restrict__ m2, const float* __restrict__ v2,
                       unsigned short* __restrict__ outb, float* __restrict__ outf,
                       int do_bn2, int do_relu2) {
    __shared__ char sA[16384];       // agg result / out-stage
    __shared__ char sZ[16384];       // z1 tile
    int tid = threadIdx.x;
    size_t nb = (size_t)blockIdx.x * 64;
    int lane16 = tid & 15;
    int grp = tid >> 4;              // 0..31, each does 2 nodes
    float epsv = 1.f + eps_arr[layer];

    // ---- Phase 1 ----
    {
        int nlA = grp * 2, nlB = nlA + 1;
        int nA = (int)nb + nlA, nB = (int)nb + nlB;
        // upfront independent loads for BOTH nodes (1 shared round-trip)
        int dgA = min(deg[nA], MAXDEG);
        int dgB = min(deg[nB], MAXDEG);
        int recA = elist[(size_t)nA * MAXDEG + lane16];
        int recB = elist[(size_t)nB * MAXDEG + lane16];
        int4 hsA = *(const int4*)(hin + (size_t)nA * D + lane16 * 8);
        int4 hsB = *(const int4*)(hin + (size_t)nB * D + lane16 * 8);

        // ---- node A ----
        {
            float z[8];
            const unsigned short* s8 = (const unsigned short*)&hsA;
#pragma unroll
            for (int t = 0; t < 8; ++t) z[t] = epsv * bf2f(s8[t]);
            int4 hv[4], bv[4];
#pragma unroll
            for (int j = 0; j < 4; ++j) {
                int r = __shfl(recA, j, 16);
                if (j < dgA) {
                    hv[j] = *(const int4*)(hin + (size_t)(r & 0x3FFFF) * D + lane16 * 8);
                    bv[j] = *(const int4*)(bsum + (size_t)((r >> 18) & 511) * D + lane16 * 8);
                }
            }
#pragma unroll
            for (int j = 0; j < 4; ++j) {
                if (j < dgA) {
                    const unsigned short* h8 = (const unsigned short*)&hv[j];
                    const unsigned short* b8 = (const unsigned short*)&bv[j];
#pragma unroll
                    for (int t = 0; t < 8; ++t)
                        z[t] += fmaxf(bf2f(h8[t]) + bf2f(b8[t]), 0.f);
                }
            }
            for (int base = 4; base < dgA && base < 16; base += 4) {   // tail (11%)
                int4 hw[4], bw[4];
#pragma unroll
                for (int j = 0; j < 4; ++j) {
                    int r = __shfl(recA, base + j, 16);
                    if (base + j < dgA) {
                        hw[j] = *(const int4*)(hin + (size_t)(r & 0x3FFFF) * D + lane16 * 8);
                        bw[j] = *(const int4*)(bsum + (size_t)((r >> 18) & 511) * D + lane16 * 8);
                    }
                }
#pragma unroll
                for (int j = 0; j < 4; ++j) {
                    if (base + j < dgA) {
                        const unsigned short* h8 = (const unsigned short*)&hw[j];
                        const unsigned short* b8 = (const unsigned short*)&bw[j];
#pragma unroll
                        for (int t = 0; t < 8; ++t)
                            z[t] += fmaxf(bf2f(h8[t]) + bf2f(b8[t]), 0.f);
                    }
                }
            }
            for (int e = 16; e < dgA; ++e) {          // ultra-rare (P ~ 1e-9)
                int r = elist[(size_t)nA * MAXDEG + e];
                int4 h4 = *(const int4*)(hin + (size_t)(r & 0x3FFFF) * D + lane16 * 8);
                int4 b4 = *(const int4*)(bsum + (size_t)((r >> 18) & 511) * D + lane16 * 8);
                const unsigned short* h8 = (const unsigned short*)&h4;
                const unsigned short* b8 = (const unsigned short*)&b4;
#pragma unroll
                for (int t = 0; t < 8; ++t)
                    z[t] += fmaxf(bf2f(h8[t]) + bf2f(b8[t]), 0.f);
            }
            unsigned short o[8];
#pragma unroll
            for (int t = 0; t < 8; ++t) o[t] = f2bf(z[t]);
            *(int4*)(sA + SWZ(nlA, lane16 * 16)) = *(int4*)o;
        }

        // ---- node B ----
        {
            float z[8];
            const unsigned short* s8 = (const unsigned short*)&hsB;
#pragma unroll
            for (int t = 0; t < 8; ++t) z[t] = epsv * bf2f(s8[t]);
            int4 hv[4], bv[4];
#pragma unroll
            for (int j = 0; j < 4; ++j) {
                int r = __shfl(recB, j, 16);
                if (j < dgB) {
                    hv[j] = *(const int4*)(hin + (size_t)(r & 0x3FFFF) * D + lane16 * 8);
                    bv[j] = *(const int4*)(bsum + (size_t)((r >> 18) & 511) * D + lane16 * 8);
                }
            }
#pragma unroll
            for (int j = 0; j < 4; ++j) {
                if (j < dgB) {
                    const unsigned short* h8 = (const unsigned short*)&hv[j];
                    const unsigned short* b8 = (const unsigned short*)&bv[j];
#pragma unroll
                    for (int t = 0; t < 8; ++t)
                        z[t] += fmaxf(bf2f(h8[t]) + bf2f(b8[t]), 0.f);
                }
            }
            for (int base = 4; base < dgB && base < 16; base += 4) {
                int4 hw[4], bw[4];
#pragma unroll
                for (int j = 0; j < 4; ++j) {
                    int r = __shfl(recB, base + j, 16);
                    if (base + j < dgB) {
                        hw[j] = *(const int4*)(hin + (size_t)(r & 0x3FFFF) * D + lane16 * 8);
                        bw[j] = *(const int4*)(bsum + (size_t)((r >> 18) & 511) * D + lane16 * 8);
                    }
                }
#pragma unroll
                for (int j = 0; j < 4; ++j) {
                    if (base + j < dgB) {
                        const unsigned short* h8 = (const unsigned short*)&hw[j];
                        const unsigned short* b8 = (const unsigned short*)&bw[j];
#pragma unroll
                        for (int t = 0; t < 8; ++t)
                            z[t] += fmaxf(bf2f(h8[t]) + bf2f(b8[t]), 0.f);
                    }
                }
            }
            for (int e = 16; e < dgB; ++e) {
                int r = elist[(size_t)nB * MAXDEG + e];
                int4 h4 = *(const int4*)(hin + (size_t)(r & 0x3FFFF) * D + lane16 * 8);
                int4 b4 = *(const int4*)(bsum + (size_t)((r >> 18) & 511) * D + lane16 * 8);
                const unsigned short* h8 = (const unsigned short*)&h4;
                const unsigned short* b8 = (const unsigned short*)&b4;
#pragma unroll
                for (int t = 0; t < 8; ++t)
                    z[t] += fmaxf(bf2f(h8[t]) + bf2f(b8[t]), 0.f);
            }
            unsigned short o[8];
#pragma unroll
            for (int t = 0; t < 8; ++t) o[t] = f2bf(z[t]);
            *(int4*)(sA + SWZ(nlB, lane16 * 16)) = *(int4*)o;
        }
    }
    __syncthreads();

    // ---- Phase 2: double GEMM ----
    int lane = tid & 63;
    int w = tid >> 6;
    int arow = lane & 15;
    int kq = (lane >> 4) * 8;
    int c = w * 16 + arow;
    bf16x8 w1f[4], w2f[4];
#pragma unroll
    for (int kb = 0; kb < 4; ++kb) {
        w1f[kb] = *(const bf16x8*)(W1t + (size_t)c * D + kb * 32 + kq);
        w2f[kb] = *(const bf16x8*)(W2t + (size_t)c * D + kb * 32 + kq);
    }

    f32x4 acc[4];
#pragma unroll
    for (int rt = 0; rt < 4; ++rt) acc[rt] = (f32x4){0.f, 0.f, 0.f, 0.f};
#pragma unroll
    for (int kb = 0; kb < 4; ++kb) {
        int k0 = kb * 32 + kq;
#pragma unroll
        for (int rt = 0; rt < 4; ++rt) {
            bf16x8 a = *(bf16x8*)(sA + SWZ(rt * 16 + arow, k0 * 2));
            acc[rt] = __builtin_amdgcn_mfma_f32_16x16x32_bf16(a, w1f[kb], acc[rt], 0, 0, 0);
        }
    }
    {
        float sc = g1[c] * rsqrtf(v1[c] + BN_EPS);
        float sh = (b1[c] - m1[c]) * sc + be1[c];
#pragma unroll
        for (int rt = 0; rt < 4; ++rt)
#pragma unroll
            for (int r = 0; r < 4; ++r) {
                int row = rt * 16 + (lane >> 4) * 4 + r;
                float z = fmaxf(acc[rt][r] * sc + sh, 0.f);
                *(unsigned short*)(sZ + SWZ(row, c * 2)) = f2bf(z);
            }
    }
    __syncthreads();

#pragma unroll
    for (int rt = 0; rt < 4; ++rt) acc[rt] = (f32x4){0.f, 0.f, 0.f, 0.f};
#pragma unroll
    for (int kb = 0; kb < 4; ++kb) {
        int k0 = kb * 32 + kq;
#pragma unroll
        for (int rt = 0; rt < 4; ++rt) {
            bf16x8 a = *(bf16x8*)(sZ + SWZ(rt * 16 + arow, k0 * 2));
            acc[rt] = __builtin_amdgcn_mfma_f32_16x16x32_bf16(a, w2f[kb], acc[rt], 0, 0, 0);
        }
    }

    float sc2 = 1.f, sh2;
    if (do_bn2) { sc2 = g2[c] * rsqrtf(v2[c] + BN_EPS); sh2 = (b2[c] - m2[c]) * sc2 + be2[c]; }
    else sh2 = b2[c];
    if constexpr (OUTF32) {
#pragma unroll
        for (int rt = 0; rt < 4; ++rt)
#pragma unroll
            for (int r = 0; r < 4; ++r) {
                int row = rt * 16 + (lane >> 4) * 4 + r;
                float z = acc[rt][r] * sc2 + sh2;
                if (do_relu2) z = fmaxf(z, 0.f);
                outf[(nb + row) * D + c] = z;
            }
    } else {
        // sA last read in GEMM1 (barrier since) -> safe to overwrite
#pragma unroll
        for (int rt = 0; rt < 4; ++rt)
#pragma unroll
            for (int r = 0; r < 4; ++r) {
                int row = rt * 16 + (lane >> 4) * 4 + r;
                float z = acc[rt][r] * sc2 + sh2;
                if (do_relu2) z = fmaxf(z, 0.f);
                *(unsigned short*)(sA + SWZ(row, c * 2)) = f2bf(z);
            }
        __syncthreads();
#pragma unroll
        for (int i = 0; i < 2; ++i) {
            int s = tid + i * 512;
            int r = s >> 4, cc = (s & 15) * 16;
            *(int4*)((char*)outb + (nb + r) * 256 + cc) = *(int4*)(sA + SWZ(r, cc));
        }
    }
}

// ---------------- launch ----------------
extern "C" void kernel_launch(void* const* d_in, const int* in_sizes, int n_in,
                              void* d_out, int out_size, void* d_ws, size_t ws_size,
                              hipStream_t stream) {
    const float* x      = (const float*)d_in[0];
    const int*   ei     = (const int*)d_in[1];
    const int*   ea     = (const int*)d_in[2];
    const float* aeW1   = (const float*)d_in[3];
    const float* aeb1   = (const float*)d_in[4];
    const float* aeg1   = (const float*)d_in[5];
    const float* aebe1  = (const float*)d_in[6];
    const float* aem1   = (const float*)d_in[7];
    const float* aev1   = (const float*)d_in[8];
    const float* aeW2   = (const float*)d_in[9];
    const float* aeb2   = (const float*)d_in[10];
    const float* aeg2   = (const float*)d_in[11];
    const float* aebe2  = (const float*)d_in[12];
    const float* aem2   = (const float*)d_in[13];
    const float* aev2   = (const float*)d_in[14];
    const float* aeW3   = (const float*)d_in[15];
    const float* aeb3   = (const float*)d_in[16];
    const float* bond   = (const float*)d_in[17];
    const float* eps    = (const float*)d_in[18];
    const float* mlpW1  = (const float*)d_in[19];
    const float* mlpb1  = (const float*)d_in[20];
    const float* mlpg   = (const float*)d_in[21];
    const float* mlpbe  = (const float*)d_in[22];
    const float* mlpm   = (const float*)d_in[23];
    const float* mlpv   = (const float*)d_in[24];
    const float* mlpW2  = (const float*)d_in[25];
    const float* mlpb2  = (const float*)d_in[26];
    const float* outg   = (const float*)d_in[27];
    const float* outbe  = (const float*)d_in[28];
    const float* outm   = (const float*)d_in[29];
    const float* outv   = (const float*)d_in[30];

    char* ws = (char*)d_ws;
    unsigned short* hA  = (unsigned short*)ws;                    // 51,200,000 B
    unsigned short* hB  = (unsigned short*)(ws + 51200000);       // 51,200,000 B
    int*   deg   = (int*)(ws + 102400000);                        // 800,000 B
    int*   elist = (int*)(ws + 103200000);                        // 19,200,000 B
    unsigned short* wbt = (unsigned short*)(ws + 122400000);      // 393,216 B
    unsigned short* bsum = (unsigned short*)(ws + 122793216);     // 655,360 B (bf16)
    float* outF = (float*)d_out;

    // CSR build + weight prep + bond-sum table
    k_zero<<<(NNODES + 255) / 256, 256, 0, stream>>>(deg, NNODES);
    k_fill_edges<<<(NEDGES + 255) / 256, 256, 0, stream>>>(ei, ea, deg, elist, NEDGES);
    k_prep_w<<<96, 256, 0, stream>>>(aeW2, aeW3, mlpW1, mlpW2, wbt);
    k_bondsum<<<NLAYERS * 512, 128, 0, stream>>>(bond, bsum);

    // atom encoder: ae1 -> hA (bf16); fused ae2+ae3: hA -> hB (bf16)
    k_ae1<<<1280, 256, 0, stream>>>(x, aeW1, aeb1, aeg1, aebe1, aem1, aev1, hA);
    dim3 gg(NNODES / 64);     // 3125, exact
    k_mlp2<0><<<gg, 512, 0, stream>>>(hA,
        wbt + 0 * 16384, aeb2, aeg2, aebe2, aem2, aev2,
        wbt + 1 * 16384, aeb3, aeb3, aeb3, aeb3, aeb3,
        hB, nullptr, 0, 0);

    // GIN layers: one fused dispatch per layer, ping-pong hB <-> hA; l=4 -> fp32 d_out
    unsigned short* hc = hB;
    for (int l = 0; l < NLAYERS; ++l) {
        unsigned short* ho = (hc == hB) ? hA : hB;
        const unsigned short* W1 = wbt + (size_t)(2 + l) * 16384;
        const unsigned short* W2 = wbt + (size_t)(7 + l) * 16384;
        if (l < NLAYERS - 1) {
            k_gin2<0><<<gg, 512, 0, stream>>>(hc, bsum + (size_t)l * 512 * 128, eps, l,
                deg, elist,
                W1, mlpb1 + (size_t)l * D, mlpg + (size_t)l * D, mlpbe + (size_t)l * D,
                mlpm + (size_t)l * D, mlpv + (size_t)l * D,
                W2, mlpb2 + (size_t)l * D, outg + (size_t)l * D, outbe + (size_t)l * D,
                outm + (size_t)l * D, outv + (size_t)l * D,
                ho, nullptr, 1, 1);
            hc = ho;
        } else {
            k_gin2<1><<<gg, 512, 0, stream>>>(hc, bsum + (size_t)l * 512 * 128, eps, l,
                deg, elist,
                W1, mlpb1 + (size_t)l * D, mlpg + (size_t)l * D, mlpbe + (size_t)l * D,
                mlpm + (size_t)l * D, mlpv + (size_t)l * D,
                W2, mlpb2 + (size_t)l * D, outg + (size_t)l * D, outbe + (size_t)l * D,
                outm + (size_t)l * D, outv + (size_t)l * D,
                nullptr, outF, 1, 0);
        }
    }
    (void)in_sizes; (void)n_in; (void)out_size; (void)ws_size;
}

// Round 14
// 423.773 us; speedup vs baseline: 1.7826x; 1.7826x over previous
//
#include <hip/hip_runtime.h>
#include <hip/hip_bf16.h>
#include <cstdint>
#include <cstddef>

#define D 128
#define NNODES 200000
#define NEDGES 500000
#define NLAYERS 5
#define BN_EPS 1e-5f
#define MAXDEG 24

typedef __attribute__((ext_vector_type(8))) short bf16x8;   // 8 bf16 in 4 VGPRs
typedef __attribute__((ext_vector_type(4))) float f32x4;    // MFMA accumulator

__device__ __forceinline__ unsigned short f2bf(float f) {
    union { float f; unsigned int u; } x; x.f = f;
    unsigned int r = (x.u + 0x7FFFu + ((x.u >> 16) & 1u)) >> 16;   // RNE
    return (unsigned short)r;
}
__device__ __forceinline__ float bf2f(unsigned short u) {
    union { unsigned int u; float f; } x; x.u = ((unsigned int)u) << 16; return x.f;
}

// ---------------- CSR build ----------------
__global__ void k_zero(int* __restrict__ p, int n) {
    int i = blockIdx.x * 256 + threadIdx.x;
    if (i < n) p[i] = 0;
}

// pack src (18 bits) + a0,a1,a2 (3 bits each) into one int per edge
__global__ void k_fill_edges(const int* __restrict__ ei, const int* __restrict__ ea,
                             int* __restrict__ deg, int* __restrict__ elist, int n_edges) {
    int e = blockIdx.x * 256 + threadIdx.x;
    if (e >= n_edges) return;
    int dst = ei[n_edges + e];
    int src = ei[e];
    int a0 = ea[e * 3], a1 = ea[e * 3 + 1], a2 = ea[e * 3 + 2];
    int rec = src | (a0 << 18) | (a1 << 21) | (a2 << 24);
    int pos = atomicAdd(&deg[dst], 1);
    if (pos < MAXDEG) elist[dst * MAXDEG + pos] = rec;
}

// ---------------- weight prep: fp32 [K][F] -> bf16 transposed [F][K] ----------------
__global__ void k_prep_w(const float* __restrict__ aeW2, const float* __restrict__ aeW3,
                         const float* __restrict__ mlpW1, const float* __restrict__ mlpW2,
                         unsigned short* __restrict__ wbt) {
    int m = blockIdx.x >> 3;                        // 0..11
    int s = (blockIdx.x & 7) * 256 + threadIdx.x;   // 0..2047
    int f = s >> 4;
    int kc = (s & 15) * 8;
    const float* W;
    if (m == 0) W = aeW2;
    else if (m == 1) W = aeW3;
    else if (m < 7) W = mlpW1 + (size_t)(m - 2) * D * D;
    else W = mlpW2 + (size_t)(m - 7) * D * D;
    unsigned short tmp[8];
#pragma unroll
    for (int j = 0; j < 8; ++j) tmp[j] = f2bf(W[(size_t)(kc + j) * D + f]);
    *(int4*)(wbt + (size_t)m * D * D + (size_t)f * D + kc) = *(int4*)tmp;
}

// ---------------- bond-sum table (bf16): bsum[l][combo][f] ----------------
// combo = a0 | a1<<3 | a2<<6  (matches rec bits 18..26)
__global__ void k_bondsum(const float* __restrict__ bond, unsigned short* __restrict__ bsum) {
    int idx = blockIdx.x;                 // 0..(NLAYERS*512-1)
    int l = idx >> 9, combo = idx & 511;
    int a0 = combo & 7, a1 = (combo >> 3) & 7, a2 = (combo >> 6) & 7;
    int f = threadIdx.x;                  // 128
    const float* bl = bond + (size_t)l * 3 * 8 * 128;
    bsum[(size_t)idx * 128 + f] =
        f2bf(bl[a0 * 128 + f] + bl[1024 + a1 * 128 + f] + bl[2048 + a2 * 128 + f]);
}

// ---------------- atom encoder layer 1 (persistent, BN folded, bf16 out) ----------------
__global__ void k_ae1(const float* __restrict__ x, const float* __restrict__ W,
                      const float* __restrict__ b, const float* __restrict__ g,
                      const float* __restrict__ be, const float* __restrict__ m,
                      const float* __restrict__ v, unsigned short* __restrict__ out) {
    __shared__ float sW[12][128];
    int tid = threadIdx.x;
    for (int i = tid; i < 12 * 128; i += 256) sW[i >> 7][i & 127] = W[i];
    int f0 = (tid & 31) * 4;
    int g8 = tid >> 5;
    float4 bb = *(const float4*)(b + f0);
    float4 gg = *(const float4*)(g + f0);
    float4 ee = *(const float4*)(be + f0);
    float4 mm = *(const float4*)(m + f0);
    float4 vv = *(const float4*)(v + f0);
    float A0 = gg.x * rsqrtf(vv.x + BN_EPS), S0 = (bb.x - mm.x) * A0 + ee.x;
    float A1 = gg.y * rsqrtf(vv.y + BN_EPS), S1 = (bb.y - mm.y) * A1 + ee.y;
    float A2 = gg.z * rsqrtf(vv.z + BN_EPS), S2 = (bb.z - mm.z) * A2 + ee.z;
    float A3 = gg.w * rsqrtf(vv.w + BN_EPS), S3 = (bb.w - mm.w) * A3 + ee.w;
    __syncthreads();
    for (int n = blockIdx.x * 8 + g8; n < NNODES; n += gridDim.x * 8) {
        const float4* xr = (const float4*)(x + (size_t)n * 12);
        float4 x0 = xr[0], x1 = xr[1], x2 = xr[2];
        float xv[12] = {x0.x, x0.y, x0.z, x0.w, x1.x, x1.y, x1.z, x1.w,
                        x2.x, x2.y, x2.z, x2.w};
        float a0 = 0.f, a1 = 0.f, a2 = 0.f, a3 = 0.f;
#pragma unroll
        for (int k = 0; k < 12; ++k) {
            float4 wv = *(float4*)&sW[k][f0];
            a0 += xv[k] * wv.x; a1 += xv[k] * wv.y;
            a2 += xv[k] * wv.z; a3 += xv[k] * wv.w;
        }
        unsigned short o[4];
        o[0] = f2bf(fmaxf(a0 * A0 + S0, 0.f));
        o[1] = f2bf(fmaxf(a1 * A1 + S1, 0.f));
        o[2] = f2bf(fmaxf(a2 * A2 + S2, 0.f));
        o[3] = f2bf(fmaxf(a3 * A3 + S3, 0.f));
        *(uint2*)(out + (size_t)n * D + f0) = *(uint2*)o;
    }
}

#define SWZ(row, bytecol) (((row) * 256 + (bytecol)) ^ (((row) & 7) << 4))

// ---------------- plain fused double GEMM (atom encoder): 64-node tile, 512 threads ----------------
template<int OUTF32>
__launch_bounds__(512, 6)
__global__ void k_mlp2(const unsigned short* __restrict__ hin,
                       const unsigned short* __restrict__ W1t, const float* __restrict__ b1,
                       const float* __restrict__ g1, const float* __restrict__ be1,
                       const float* __restrict__ m1, const float* __restrict__ v1,
                       const unsigned short* __restrict__ W2t, const float* __restrict__ b2,
                       const float* __restrict__ g2, const float* __restrict__ be2,
                       const float* __restrict__ m2, const float* __restrict__ v2,
                       unsigned short* __restrict__ outb, float* __restrict__ outf,
                       int do_bn2, int do_relu2) {
    __shared__ char sA[16384];
    __shared__ char sZ[16384];
    int tid = threadIdx.x;
    size_t nb = (size_t)blockIdx.x * 64;
    int lane = tid & 63;
    int w = tid >> 6;
    int arow = lane & 15;
    int kq = (lane >> 4) * 8;
    int c = w * 16 + arow;

    bf16x8 w1f[4], w2f[4];
#pragma unroll
    for (int kb = 0; kb < 4; ++kb) {
        w1f[kb] = *(const bf16x8*)(W1t + (size_t)c * D + kb * 32 + kq);
        w2f[kb] = *(const bf16x8*)(W2t + (size_t)c * D + kb * 32 + kq);
    }
#pragma unroll
    for (int i = 0; i < 2; ++i) {
        int s = tid + i * 512;
        int r = s >> 4, cc = (s & 15) * 16;
        *(int4*)(sA + SWZ(r, cc)) = *(const int4*)((const char*)hin + (nb + r) * 256 + cc);
    }
    __syncthreads();

    f32x4 acc[4];
#pragma unroll
    for (int rt = 0; rt < 4; ++rt) acc[rt] = (f32x4){0.f, 0.f, 0.f, 0.f};
#pragma unroll
    for (int kb = 0; kb < 4; ++kb) {
        int k0 = kb * 32 + kq;
#pragma unroll
        for (int rt = 0; rt < 4; ++rt) {
            bf16x8 a = *(bf16x8*)(sA + SWZ(rt * 16 + arow, k0 * 2));
            acc[rt] = __builtin_amdgcn_mfma_f32_16x16x32_bf16(a, w1f[kb], acc[rt], 0, 0, 0);
        }
    }
    {
        float sc = g1[c] * rsqrtf(v1[c] + BN_EPS);
        float sh = (b1[c] - m1[c]) * sc + be1[c];
#pragma unroll
        for (int rt = 0; rt < 4; ++rt)
#pragma unroll
            for (int r = 0; r < 4; ++r) {
                int row = rt * 16 + (lane >> 4) * 4 + r;
                float z = fmaxf(acc[rt][r] * sc + sh, 0.f);
                *(unsigned short*)(sZ + SWZ(row, c * 2)) = f2bf(z);
            }
    }
    __syncthreads();

#pragma unroll
    for (int rt = 0; rt < 4; ++rt) acc[rt] = (f32x4){0.f, 0.f, 0.f, 0.f};
#pragma unroll
    for (int kb = 0; kb < 4; ++kb) {
        int k0 = kb * 32 + kq;
#pragma unroll
        for (int rt = 0; rt < 4; ++rt) {
            bf16x8 a = *(bf16x8*)(sZ + SWZ(rt * 16 + arow, k0 * 2));
            acc[rt] = __builtin_amdgcn_mfma_f32_16x16x32_bf16(a, w2f[kb], acc[rt], 0, 0, 0);
        }
    }

    float sc2 = 1.f, sh2;
    if (do_bn2) { sc2 = g2[c] * rsqrtf(v2[c] + BN_EPS); sh2 = (b2[c] - m2[c]) * sc2 + be2[c]; }
    else sh2 = b2[c];
    if constexpr (OUTF32) {
#pragma unroll
        for (int rt = 0; rt < 4; ++rt)
#pragma unroll
            for (int r = 0; r < 4; ++r) {
                int row = rt * 16 + (lane >> 4) * 4 + r;
                float z = acc[rt][r] * sc2 + sh2;
                if (do_relu2) z = fmaxf(z, 0.f);
                outf[(nb + row) * D + c] = z;
            }
    } else {
#pragma unroll
        for (int rt = 0; rt < 4; ++rt)
#pragma unroll
            for (int r = 0; r < 4; ++r) {
                int row = rt * 16 + (lane >> 4) * 4 + r;
                float z = acc[rt][r] * sc2 + sh2;
                if (do_relu2) z = fmaxf(z, 0.f);
                *(unsigned short*)(sA + SWZ(row, c * 2)) = f2bf(z);
            }
        __syncthreads();
#pragma unroll
        for (int i = 0; i < 2; ++i) {
            int s = tid + i * 512;
            int r = s >> 4, cc = (s & 15) * 16;
            *(int4*)((char*)outb + (nb + r) * 256 + cc) = *(int4*)(sA + SWZ(r, cc));
        }
    }
}

// ---------------- FUSED GIN layer: gather-aggregate -> double GEMM, one dispatch ----------------
// Phase 1 (gather): 16 groups x 32 lanes; each group aggregates 4 nodes with conditional
// 6-deep batch — the round-9 configuration, the unique no-spill local optimum (VGPR=40).
// Phase 2: W frags global->reg (L2-hot), GEMM1 -> sZ -> GEMM2 -> out (bf16 or fp32).
template<int OUTF32>
__launch_bounds__(512, 5)
__global__ void k_gin2(const unsigned short* __restrict__ hin,
                       const unsigned short* __restrict__ bsum,   // bf16 [512][128] this layer
                       const float* __restrict__ eps_arr, int layer,
                       const int* __restrict__ deg, const int* __restrict__ elist,
                       const unsigned short* __restrict__ W1t, const float* __restrict__ b1,
                       const float* __restrict__ g1, const float* __restrict__ be1,
                       const float* __restrict__ m1, const float* __restrict__ v1,
                       const unsigned short* __restrict__ W2t, const float* __restrict__ b2,
                       const float* __restrict__ g2, const float* __restrict__ be2,
                       const float* __restrict__ m2, const float* __restrict__ v2,
                       unsigned short* __restrict__ outb, float* __restrict__ outf,
                       int do_bn2, int do_relu2) {
    __shared__ char sA[16384];       // agg result / out-stage
    __shared__ char sZ[16384];       // z1 tile
    int tid = threadIdx.x;
    size_t nb = (size_t)blockIdx.x * 64;
    int f4 = tid & 31;
    int grp = tid >> 5;              // 0..15, each does 4 nodes
    float epsv = 1.f + eps_arr[layer];

    // ---- Phase 1: aggregate 4 nodes per group ----
    for (int u = 0; u < 4; ++u) {
        int nl = grp * 4 + u;
        int n = (int)nb + nl;
        int dgr = min(deg[n], MAXDEG);
        int rec = (f4 < MAXDEG) ? elist[(size_t)n * MAXDEG + f4] : 0;
        ushort4 hs = *(const ushort4*)(hin + (size_t)n * D + f4 * 4);
        float z0 = epsv * bf2f(hs.x), z1 = epsv * bf2f(hs.y);
        float z2 = epsv * bf2f(hs.z), z3 = epsv * bf2f(hs.w);
        ushort4 hv[6]; ushort4 bv[6]; int rr[6];
#pragma unroll
        for (int j = 0; j < 6; ++j) {
            rr[j] = __shfl(rec, j, 32);
            if (j < dgr) {
                hv[j] = *(const ushort4*)(hin + (size_t)(rr[j] & 0x3FFFF) * D + f4 * 4);
                bv[j] = *(const ushort4*)(bsum + (size_t)((rr[j] >> 18) & 511) * D + f4 * 4);
            }
        }
#pragma unroll
        for (int j = 0; j < 6; ++j) {
            if (j < dgr) {
                z0 += fmaxf(bf2f(hv[j].x) + bf2f(bv[j].x), 0.f);
                z1 += fmaxf(bf2f(hv[j].y) + bf2f(bv[j].y), 0.f);
                z2 += fmaxf(bf2f(hv[j].z) + bf2f(bv[j].z), 0.f);
                z3 += fmaxf(bf2f(hv[j].w) + bf2f(bv[j].w), 0.f);
            }
        }
        for (int base = 6; base < dgr; base += 4) {   // rare tail (P ~ 1.4%)
            ushort4 hw[4]; ushort4 bw[4]; int rt[4];
#pragma unroll
            for (int j = 0; j < 4; ++j) {
                rt[j] = __shfl(rec, base + j, 32);
                if (base + j < dgr) {
                    hw[j] = *(const ushort4*)(hin + (size_t)(rt[j] & 0x3FFFF) * D + f4 * 4);
                    bw[j] = *(const ushort4*)(bsum + (size_t)((rt[j] >> 18) & 511) * D + f4 * 4);
                }
            }
#pragma unroll
            for (int j = 0; j < 4; ++j) {
                if (base + j < dgr) {
                    z0 += fmaxf(bf2f(hw[j].x) + bf2f(bw[j].x), 0.f);
                    z1 += fmaxf(bf2f(hw[j].y) + bf2f(bw[j].y), 0.f);
                    z2 += fmaxf(bf2f(hw[j].z) + bf2f(bw[j].z), 0.f);
                    z3 += fmaxf(bf2f(hw[j].w) + bf2f(bw[j].w), 0.f);
                }
            }
        }
        unsigned short o[4] = {f2bf(z0), f2bf(z1), f2bf(z2), f2bf(z3)};
        *(uint2*)(sA + SWZ(nl, f4 * 8)) = *(uint2*)o;
    }
    __syncthreads();

    // ---- Phase 2: double GEMM ----
    int lane = tid & 63;
    int w = tid >> 6;
    int arow = lane & 15;
    int kq = (lane >> 4) * 8;
    int c = w * 16 + arow;
    bf16x8 w1f[4], w2f[4];
#pragma unroll
    for (int kb = 0; kb < 4; ++kb) {
        w1f[kb] = *(const bf16x8*)(W1t + (size_t)c * D + kb * 32 + kq);
        w2f[kb] = *(const bf16x8*)(W2t + (size_t)c * D + kb * 32 + kq);
    }

    f32x4 acc[4];
#pragma unroll
    for (int rt = 0; rt < 4; ++rt) acc[rt] = (f32x4){0.f, 0.f, 0.f, 0.f};
#pragma unroll
    for (int kb = 0; kb < 4; ++kb) {
        int k0 = kb * 32 + kq;
#pragma unroll
        for (int rt = 0; rt < 4; ++rt) {
            bf16x8 a = *(bf16x8*)(sA + SWZ(rt * 16 + arow, k0 * 2));
            acc[rt] = __builtin_amdgcn_mfma_f32_16x16x32_bf16(a, w1f[kb], acc[rt], 0, 0, 0);
        }
    }
    {
        float sc = g1[c] * rsqrtf(v1[c] + BN_EPS);
        float sh = (b1[c] - m1[c]) * sc + be1[c];
#pragma unroll
        for (int rt = 0; rt < 4; ++rt)
#pragma unroll
            for (int r = 0; r < 4; ++r) {
                int row = rt * 16 + (lane >> 4) * 4 + r;
                float z = fmaxf(acc[rt][r] * sc + sh, 0.f);
                *(unsigned short*)(sZ + SWZ(row, c * 2)) = f2bf(z);
            }
    }
    __syncthreads();

#pragma unroll
    for (int rt = 0; rt < 4; ++rt) acc[rt] = (f32x4){0.f, 0.f, 0.f, 0.f};
#pragma unroll
    for (int kb = 0; kb < 4; ++kb) {
        int k0 = kb * 32 + kq;
#pragma unroll
        for (int rt = 0; rt < 4; ++rt) {
            bf16x8 a = *(bf16x8*)(sZ + SWZ(rt * 16 + arow, k0 * 2));
            acc[rt] = __builtin_amdgcn_mfma_f32_16x16x32_bf16(a, w2f[kb], acc[rt], 0, 0, 0);
        }
    }

    float sc2 = 1.f, sh2;
    if (do_bn2) { sc2 = g2[c] * rsqrtf(v2[c] + BN_EPS); sh2 = (b2[c] - m2[c]) * sc2 + be2[c]; }
    else sh2 = b2[c];
    if constexpr (OUTF32) {
#pragma unroll
        for (int rt = 0; rt < 4; ++rt)
#pragma unroll
            for (int r = 0; r < 4; ++r) {
                int row = rt * 16 + (lane >> 4) * 4 + r;
                float z = acc[rt][r] * sc2 + sh2;
                if (do_relu2) z = fmaxf(z, 0.f);
                outf[(nb + row) * D + c] = z;
            }
    } else {
        // sA last read in GEMM1 (barrier since) -> safe to overwrite
#pragma unroll
        for (int rt = 0; rt < 4; ++rt)
#pragma unroll
            for (int r = 0; r < 4; ++r) {
                int row = rt * 16 + (lane >> 4) * 4 + r;
                float z = acc[rt][r] * sc2 + sh2;
                if (do_relu2) z = fmaxf(z, 0.f);
                *(unsigned short*)(sA + SWZ(row, c * 2)) = f2bf(z);
            }
        __syncthreads();
#pragma unroll
        for (int i = 0; i < 2; ++i) {
            int s = tid + i * 512;
            int r = s >> 4, cc = (s & 15) * 16;
            *(int4*)((char*)outb + (nb + r) * 256 + cc) = *(int4*)(sA + SWZ(r, cc));
        }
    }
}

// ---------------- launch ----------------
extern "C" void kernel_launch(void* const* d_in, const int* in_sizes, int n_in,
                              void* d_out, int out_size, void* d_ws, size_t ws_size,
                              hipStream_t stream) {
    const float* x      = (const float*)d_in[0];
    const int*   ei     = (const int*)d_in[1];
    const int*   ea     = (const int*)d_in[2];
    const float* aeW1   = (const float*)d_in[3];
    const float* aeb1   = (const float*)d_in[4];
    const float* aeg1   = (const float*)d_in[5];
    const float* aebe1  = (const float*)d_in[6];
    const float* aem1   = (const float*)d_in[7];
    const float* aev1   = (const float*)d_in[8];
    const float* aeW2   = (const float*)d_in[9];
    const float* aeb2   = (const float*)d_in[10];
    const float* aeg2   = (const float*)d_in[11];
    const float* aebe2  = (const float*)d_in[12];
    const float* aem2   = (const float*)d_in[13];
    const float* aev2   = (const float*)d_in[14];
    const float* aeW3   = (const float*)d_in[15];
    const float* aeb3   = (const float*)d_in[16];
    const float* bond   = (const float*)d_in[17];
    const float* eps    = (const float*)d_in[18];
    const float* mlpW1  = (const float*)d_in[19];
    const float* mlpb1  = (const float*)d_in[20];
    const float* mlpg   = (const float*)d_in[21];
    const float* mlpbe  = (const float*)d_in[22];
    const float* mlpm   = (const float*)d_in[23];
    const float* mlpv   = (const float*)d_in[24];
    const float* mlpW2  = (const float*)d_in[25];
    const float* mlpb2  = (const float*)d_in[26];
    const float* outg   = (const float*)d_in[27];
    const float* outbe  = (const float*)d_in[28];
    const float* outm   = (const float*)d_in[29];
    const float* outv   = (const float*)d_in[30];

    char* ws = (char*)d_ws;
    unsigned short* hA  = (unsigned short*)ws;                    // 51,200,000 B
    unsigned short* hB  = (unsigned short*)(ws + 51200000);       // 51,200,000 B
    int*   deg   = (int*)(ws + 102400000);                        // 800,000 B
    int*   elist = (int*)(ws + 103200000);                        // 19,200,000 B
    unsigned short* wbt = (unsigned short*)(ws + 122400000);      // 393,216 B
    unsigned short* bsum = (unsigned short*)(ws + 122793216);     // 655,360 B (bf16)
    float* outF = (float*)d_out;

    // CSR build + weight prep + bond-sum table
    k_zero<<<(NNODES + 255) / 256, 256, 0, stream>>>(deg, NNODES);
    k_fill_edges<<<(NEDGES + 255) / 256, 256, 0, stream>>>(ei, ea, deg, elist, NEDGES);
    k_prep_w<<<96, 256, 0, stream>>>(aeW2, aeW3, mlpW1, mlpW2, wbt);
    k_bondsum<<<NLAYERS * 512, 128, 0, stream>>>(bond, bsum);

    // atom encoder: ae1 -> hA (bf16); fused ae2+ae3: hA -> hB (bf16)
    k_ae1<<<1280, 256, 0, stream>>>(x, aeW1, aeb1, aeg1, aebe1, aem1, aev1, hA);
    dim3 gg(NNODES / 64);     // 3125, exact
    k_mlp2<0><<<gg, 512, 0, stream>>>(hA,
        wbt + 0 * 16384, aeb2, aeg2, aebe2, aem2, aev2,
        wbt + 1 * 16384, aeb3, aeb3, aeb3, aeb3, aeb3,
        hB, nullptr, 0, 0);

    // GIN layers: one fused dispatch per layer, ping-pong hB <-> hA; l=4 -> fp32 d_out
    unsigned short* hc = hB;
    for (int l = 0; l < NLAYERS; ++l) {
        unsigned short* ho = (hc == hB) ? hA : hB;
        const unsigned short* W1 = wbt + (size_t)(2 + l) * 16384;
        const unsigned short* W2 = wbt + (size_t)(7 + l) * 16384;
        if (l < NLAYERS - 1) {
            k_gin2<0><<<gg, 512, 0, stream>>>(hc, bsum + (size_t)l * 512 * 128, eps, l,
                deg, elist,
                W1, mlpb1 + (size_t)l * D, mlpg + (size_t)l * D, mlpbe + (size_t)l * D,
                mlpm + (size_t)l * D, mlpv + (size_t)l * D,
                W2, mlpb2 + (size_t)l * D, outg + (size_t)l * D, outbe + (size_t)l * D,
                outm + (size_t)l * D, outv + (size_t)l * D,
                ho, nullptr, 1, 1);
            hc = ho;
        } else {
            k_gin2<1><<<gg, 512, 0, stream>>>(hc, bsum + (size_t)l * 512 * 128, eps, l,
                deg, elist,
                W1, mlpb1 + (size_t)l * D, mlpg + (size_t)l * D, mlpbe + (size_t)l * D,
                mlpm + (size_t)l * D, mlpv + (size_t)l * D,
                W2, mlpb2 + (size_t)l * D, outg + (size_t)l * D, outbe + (size_t)l * D,
                outm + (size_t)l * D, outv + (size_t)l * D,
                nullptr, outF, 1, 0);
        }
    }
    (void)in_sizes; (void)n_in; (void)out_size; (void)ws_size;
}